// Round 2
// baseline (708.538 us; speedup 1.0000x reference)
//
#include <hip/hip_runtime.h>
#include <hip/hip_bf16.h>

#define WIDTH   1024
#define HALF_W  512
#define DEPTH   8
#define BDEPTH  10
#define BATCH   65536
#define ROWS    16          // batch rows per block
#define S_R     32          // LDS row stride within a slice (elements)
#define S_H     520         // LDS slice stride (16*32 + 8 pad; 1040 B, 16B aligned)

typedef _Float16 v8h __attribute__((ext_vector_type(8)));   // 8 x fp16 (MFMA A/B frag)
typedef float    v4f __attribute__((ext_vector_type(4)));   // MFMA C/D frag

static __device__ __forceinline__ unsigned short f2h(float x) {
    _Float16 h = (_Float16)x;                 // RNE, rel err <= 2^-11
    return __builtin_bit_cast(unsigned short, h);
}

// ---------------------------------------------------------------------------
// Setup: compose 5 butterfly steps into 32x32 matrices, write in B-frag order.
// grid = 8 layers * 2 phases * 32 groups = 512 blocks of 64 threads.
// Block id = L*64 + ph*32 + grp.
// Phase 0 (steps t=0..4): group = g (low 5 bits of position), matrix over h.
// Phase 1 (steps t=5..9): group = h (high 5 bits), matrix over g.
// Output entry [bid*1024 + nt*512 + lane*8 + j] = M[n][k],
//   n = nt*16 + (lane&15), k = (lane>>4)*8 + j   (B[k][n] = M[n][k]).
// ---------------------------------------------------------------------------
__global__ void gen_mats(const float* __restrict__ bp, unsigned short* __restrict__ mats)
{
    const int bid = blockIdx.x;
    const int grp = bid & 31;
    const int ph  = (bid >> 5) & 1;
    const int L   = bid >> 6;
    const int tid = threadIdx.x;

    __shared__ float M[2][32][32];

    for (int i = tid; i < 1024; i += 64)
        M[0][i >> 5][i & 31] = ((i >> 5) == (i & 31)) ? 1.0f : 0.0f;
    __syncthreads();

    int buf = 0;
    for (int s = 0; s < 5; ++s) {
        const int t = ph * 5 + s;
        const int stride = 1 << (4 - s);   // pair bit within the 32-dim
        for (int idx = tid; idx < 512; idx += 64) {
            const int a  = idx >> 5;       // pair index 0..15
            const int c  = idx & 31;       // column
            const int lo = ((a & ~(stride - 1)) << 1) | (a & (stride - 1));
            const int hi = lo | stride;
            const int p_low = (ph == 0) ? ((lo << 5) | grp) : ((grp << 5) | lo);
            // theta index: rol_t(p) over 10 bits, then &511
            const int j = (((p_low << t) | (p_low >> (10 - t))) & 1023) & 511;
            const float theta = bp[L * (HALF_W * BDEPTH) + j * BDEPTH + t];
            float sn, cs;
            sincosf(theta, &sn, &cs);
            const float xl = M[buf][lo][c];
            const float xh = M[buf][hi][c];
            M[1 - buf][lo][c] =  cs * xl + sn * xh;
            M[1 - buf][hi][c] = -sn * xl + cs * xh;
        }
        buf = 1 - buf;
        __syncthreads();
    }

    unsigned short* out = mats + (size_t)bid * 1024;
    for (int i = tid; i < 1024; i += 64) {
        const int nt   = i >> 9;
        const int lane = (i >> 3) & 63;
        const int jj   = i & 7;
        const int n = nt * 16 + (lane & 15);
        const int k = (lane >> 4) * 8 + jj;
        out[i] = f2h(M[buf][n][k]);
    }
}

// ---------------------------------------------------------------------------
// Main: 16 rows per block, 256 threads (4 waves). Per layer:
//   phase 1: OUT[row][h] = sum_h' IN[row][h'] * M1_g[h][h']   (per g slice)
//   phase 2: OUT[row][g] = sum_g' IN[row][g'] * M2_h[g][g']   (per h slice)
// X1 view: [g][row][h] (slice stride S_H); X2 view: [h][row][g].
// Wave w owns group octet {8w..8w+7}, processed as two quads so the
// transposed write-back packs 4 fp16 into one ds_write_b64.
// ---------------------------------------------------------------------------
__global__ void __launch_bounds__(256, 2) butterfly_net(
    const float* __restrict__ X,
    const unsigned short* __restrict__ mats,
    const float* __restrict__ bias,
    const float* __restrict__ slope,
    const float* __restrict__ scale,
    float* __restrict__ out)
{
    __shared__ unsigned short X1[32 * S_H];
    __shared__ unsigned short X2[32 * S_H];

    const int tid  = threadIdx.x;
    const int lane = tid & 63;
    const int w    = tid >> 6;      // wave 0..3
    const int lw   = lane & 15;
    const int q    = lane >> 4;
    const int row0 = blockIdx.x * ROWS;

    // ---- load 16 rows (fp32, coalesced) -> X1 fp16, layout [g][row][h]
    for (int it = 0; it < 16; ++it) {
        const int f = (it * 256 + tid) * 4;         // 0..16383
        const int r = f >> 10;
        const int c = f & 1023;
        const float4 v = *(const float4*)(X + (size_t)(row0 + r) * WIDTH + c);
        const int h  = c >> 5;
        const int g0 = c & 31;                       // multiple of 4
        X1[(g0 + 0) * S_H + r * S_R + h] = f2h(v.x);
        X1[(g0 + 1) * S_H + r * S_R + h] = f2h(v.y);
        X1[(g0 + 2) * S_H + r * S_R + h] = f2h(v.z);
        X1[(g0 + 3) * S_H + r * S_R + h] = f2h(v.w);
    }
    __syncthreads();

    for (int L = 0; L < DEPTH; ++L) {
        // ================= phase 1: mix h (per g) =================
        const unsigned short* m1 = mats + (size_t)(L * 2 + 0) * 32 * 1024;
        for (int s = 0; s < 2; ++s) {
            const int gbase = w * 8 + s * 4;
            v4f C[4][2];
            #pragma unroll
            for (int gi = 0; gi < 4; ++gi) {
                const int g = gbase + gi;
                const v8h A = *(const v8h*)&X1[g * S_H + lw * S_R + q * 8];
                #pragma unroll
                for (int nt = 0; nt < 2; ++nt) {
                    const v8h B = *(const v8h*)&m1[(size_t)g * 1024 + nt * 512 + lane * 8];
                    C[gi][nt] = __builtin_amdgcn_mfma_f32_16x16x32_f16(
                        A, B, (v4f){0.0f, 0.0f, 0.0f, 0.0f}, 0, 0, 0);
                }
            }
            #pragma unroll
            for (int nt = 0; nt < 2; ++nt) {
                const int hout = nt * 16 + lw;
                #pragma unroll
                for (int r = 0; r < 4; ++r) {
                    const int row = q * 4 + r;
                    ushort4 pk;
                    pk.x = f2h(C[0][nt][r]);
                    pk.y = f2h(C[1][nt][r]);
                    pk.z = f2h(C[2][nt][r]);
                    pk.w = f2h(C[3][nt][r]);
                    *(ushort4*)&X2[hout * S_H + row * S_R + gbase] = pk;
                }
            }
        }
        __syncthreads();

        // ================= phase 2: mix g (per h), + activation =================
        const unsigned short* m2 = mats + (size_t)(L * 2 + 1) * 32 * 1024;
        const bool last = (L == DEPTH - 1);
        for (int s = 0; s < 2; ++s) {
            const int hbase = w * 8 + s * 4;
            v4f C[4][2];
            #pragma unroll
            for (int hi2 = 0; hi2 < 4; ++hi2) {
                const int h = hbase + hi2;
                const v8h A = *(const v8h*)&X2[h * S_H + lw * S_R + q * 8];
                #pragma unroll
                for (int nt = 0; nt < 2; ++nt) {
                    const v8h B = *(const v8h*)&m2[(size_t)h * 1024 + nt * 512 + lane * 8];
                    C[hi2][nt] = __builtin_amdgcn_mfma_f32_16x16x32_f16(
                        A, B, (v4f){0.0f, 0.0f, 0.0f, 0.0f}, 0, 0, 0);
                }
            }
            if (!last) {
                #pragma unroll
                for (int nt = 0; nt < 2; ++nt) {
                    const int gout = nt * 16 + lw;
                    float bia[4], slo[4], sca[4], rsc[4];
                    #pragma unroll
                    for (int hi2 = 0; hi2 < 4; ++hi2) {
                        const int p = (hbase + hi2) * 32 + gout;
                        bia[hi2] = bias [L * WIDTH + p];
                        slo[hi2] = slope[L * WIDTH + p];
                        sca[hi2] = scale[L * WIDTH + p];
                        rsc[hi2] = 1.0f / sca[hi2];
                    }
                    #pragma unroll
                    for (int r = 0; r < 4; ++r) {
                        const int row = q * 4 + r;
                        ushort4 pk;
                        unsigned short* pp = (unsigned short*)&pk;
                        #pragma unroll
                        for (int hi2 = 0; hi2 < 4; ++hi2) {
                            const float x = C[hi2][nt][r];
                            float u = (x * slo[hi2] - bia[hi2]) * rsc[hi2];
                            u = fminf(1.0f, fmaxf(-1.0f, u));
                            const float u2 = u * u;
                            const float y = sca[hi2] *
                                (u * (1.875f + u2 * (-1.25f + 0.375f * u2)));
                            pp[hi2] = f2h(y);
                        }
                        *(ushort4*)&X1[gout * S_H + row * S_R + hbase] = pk;
                    }
                }
            } else {
                #pragma unroll
                for (int nt = 0; nt < 2; ++nt) {
                    const int gout = nt * 16 + lw;
                    #pragma unroll
                    for (int hi2 = 0; hi2 < 4; ++hi2) {
                        const int h = hbase + hi2;
                        #pragma unroll
                        for (int r = 0; r < 4; ++r) {
                            const int row = q * 4 + r;
                            out[(size_t)(row0 + row) * WIDTH + h * 32 + gout] =
                                C[hi2][nt][r];
                        }
                    }
                }
            }
        }
        __syncthreads();
    }
}

extern "C" void kernel_launch(void* const* d_in, const int* in_sizes, int n_in,
                              void* d_out, int out_size, void* d_ws, size_t ws_size,
                              hipStream_t stream)
{
    const float* X     = (const float*)d_in[0];
    const float* bp    = (const float*)d_in[1];
    const float* bias  = (const float*)d_in[2];
    const float* slope = (const float*)d_in[3];
    const float* scale = (const float*)d_in[4];
    unsigned short* mats = (unsigned short*)d_ws;   // 512 * 1024 * 2B = 1 MB

    hipLaunchKernelGGL(gen_mats, dim3(512), dim3(64), 0, stream, bp, mats);
    hipLaunchKernelGGL(butterfly_net, dim3(BATCH / ROWS), dim3(256), 0, stream,
                       X, mats, bias, slope, scale, (float*)d_out);
}